// Round 2
// baseline (1143.523 us; speedup 1.0000x reference)
//
#include <hip/hip_runtime.h>
#include <hip/hip_bf16.h>

#define BB 64
#define CC 32
#define HW2 256   // 16*16
#define VV 4096
#define NELEM (BB*CC*HW2)   // 524288

// ---------------- workspace layout (floats) ----------------
#define OFF_F    0
#define OFF_FHAT (OFF_F    + NELEM)        // 524288
#define OFF_EMB  (OFF_FHAT + NELEM)        // 1048576
#define OFF_ESQ  (OFF_EMB  + VV*CC)        // 1179648
#define OFF_PW   (OFF_ESQ  + VV)           // 1183744
#define OFF_PB   (OFF_PW   + 4*CC*CC*9)    // 1220608
#define OFF_REST (OFF_PB   + 4*CC)         // 1220736
#define OFF_CD   (OFF_REST + NELEM)        // 1745024
#define OFF_CI   (OFF_CD   + 65536)        // 1810560
#define OFF_IDX  (OFF_CI   + 65536)        // 1876096
#define OFF_LOSS (OFF_IDX  + 16384)        // 1892480
#define OFF_FLAG (OFF_LOSS + 1)            // 1892481

// ---------------- dtype probe: is input 0 f32 (1) or bf16 (0)? ----------------
// f32 data misread as bf16: even elements are float mantissa halves -> wild
// exponents; ~46% of them exceed 1e3 or are NaN. Real bf16 N(0,1) data: 0 hits.
__global__ void k_probe(const void* __restrict__ fin, int* __restrict__ flag) {
    __shared__ int cnt[256];
    int t = threadIdx.x;
    const __hip_bfloat16* p = (const __hip_bfloat16*)fin;
    int local = 0;
    for (int i = t; i < 8192; i += 256) {
        float v = __bfloat162float(p[i]);
        if (!(fabsf(v) < 1e3f)) local++;   // also true for NaN
    }
    cnt[t] = local;
    __syncthreads();
    for (int s = 128; s > 0; s >>= 1) {
        if (t < s) cnt[t] += cnt[t + s];
        __syncthreads();
    }
    if (t == 0) *flag = (cnt[0] >= 64) ? 1 : 0;   // 1 => inputs are f32
}

// ---------------- prep: decode -> f32 ws, zero f_hat & loss ----------------
__global__ void k_prep(const void* __restrict__ fin,
                       const void* __restrict__ ein,
                       const void* __restrict__ win,
                       const void* __restrict__ bin_,
                       const int* __restrict__ flag,
                       float* __restrict__ f, float* __restrict__ fhat,
                       float* __restrict__ emb, float* __restrict__ pw,
                       float* __restrict__ pb, float* __restrict__ loss) {
    bool isf32 = (*flag != 0);
    int i = blockIdx.x * 256 + threadIdx.x;
    if (i < NELEM) {
        f[i] = isf32 ? ((const float*)fin)[i]
                     : __bfloat162float(((const __hip_bfloat16*)fin)[i]);
        fhat[i] = 0.f;
    }
    if (i < VV*CC)
        emb[i] = isf32 ? ((const float*)ein)[i]
                       : __bfloat162float(((const __hip_bfloat16*)ein)[i]);
    if (i < 4*CC*CC*9)
        pw[i] = isf32 ? ((const float*)win)[i]
                      : __bfloat162float(((const __hip_bfloat16*)win)[i]);
    if (i < 4*CC)
        pb[i] = isf32 ? ((const float*)bin_)[i]
                      : __bfloat162float(((const __hip_bfloat16*)bin_)[i]);
    if (i == 0) *loss = 0.f;
}

__global__ void k_esq(const float* __restrict__ emb, float* __restrict__ esq) {
    int v = blockIdx.x * 256 + threadIdx.x;
    if (v >= VV) return;
    const float* e = emb + v * CC;
    float s = 0.f;
    #pragma unroll
    for (int c = 0; c < CC; ++c) s = fmaf(e[c], e[c], s);
    esq[v] = s;
}

// ---------------- adaptive avg pool of (f - f_hat) -> rest[n][c] ----------------
__global__ void k_pool(const float* __restrict__ f, const float* __restrict__ fhat,
                       float* __restrict__ rest, int pn) {
    int id = blockIdx.x * 256 + threadIdx.x;
    int nn = pn * pn;
    int Ntot = BB * nn;
    if (id >= Ntot * CC) return;
    int c = id & 31, n = id >> 5;
    int cell = n % nn, b = n / nn;
    int i = cell / pn, j = cell % pn;
    int s0 = (i * 16) / pn, e0 = ((i + 1) * 16 + pn - 1) / pn;
    int s1 = (j * 16) / pn, e1 = ((j + 1) * 16 + pn - 1) / pn;
    float inv = 1.f / (float)((e0 - s0) * (e1 - s1));
    const float* fb = f + (b * CC + c) * HW2;
    const float* hb = fhat + (b * CC + c) * HW2;
    float s = 0.f;
    for (int h = s0; h < e0; ++h)
        for (int w = s1; w < e1; ++w)
            s += fb[h * 16 + w] - hb[h * 16 + w];
    rest[id] = s * inv;
}

// ---------------- argmin stage 1: lane=vector, slice of codes per block ----------------
__global__ void k_argmin1(const float* __restrict__ rest, const float* __restrict__ emb,
                          const float* __restrict__ esq, float* __restrict__ cd,
                          int* __restrict__ ci, int Ntot, int cpw) {
    int lane = threadIdx.x;
    int n = blockIdx.x * 64 + lane;
    int v0 = blockIdx.y * cpw;
    const float* xr = rest + n * CC;
    float x[CC];
    #pragma unroll
    for (int c = 0; c < CC; c += 4) {
        float4 t = *(const float4*)(xr + c);
        x[c] = t.x; x[c+1] = t.y; x[c+2] = t.z; x[c+3] = t.w;
    }
    float xx = 0.f;
    #pragma unroll
    for (int c = 0; c < CC; ++c) xx = fmaf(x[c], x[c], xx);
    float bd = 3.4e38f;
    int bi = 0;
    #pragma unroll 2
    for (int v = v0; v < v0 + cpw; ++v) {
        const float* e = emb + v * CC;   // uniform across wave -> s_load
        float d0 = 0.f, d1 = 0.f, d2 = 0.f, d3 = 0.f;
        #pragma unroll
        for (int c = 0; c < CC; c += 4) {
            d0 = fmaf(x[c],   e[c],   d0);
            d1 = fmaf(x[c+1], e[c+1], d1);
            d2 = fmaf(x[c+2], e[c+2], d2);
            d3 = fmaf(x[c+3], e[c+3], d3);
        }
        float dist = (xx + esq[v]) - 2.f * ((d0 + d1) + (d2 + d3));
        if (dist < bd) { bd = dist; bi = v; }
    }
    cd[blockIdx.y * Ntot + n] = bd;
    ci[blockIdx.y * Ntot + n] = bi;
}

// ---------------- argmin stage 2: merge slices (ascending code order, strict <) --------
__global__ void k_argmin2(const float* __restrict__ cd, const int* __restrict__ ci,
                          int* __restrict__ idx, int Ntot, int Sp) {
    int n = blockIdx.x * 256 + threadIdx.x;
    if (n >= Ntot) return;
    float bd = cd[n];
    int bi = ci[n];
    for (int s = 1; s < Sp; ++s) {
        float d = cd[s * Ntot + n];
        if (d < bd) { bd = d; bi = ci[s * Ntot + n]; }
    }
    idx[n] = bi;
}

// ---------------- fused: gather + bilinear upsample + conv3x3(phi) + f_hat += + loss ----
__global__ void k_fuse(const float* __restrict__ emb, const int* __restrict__ idx,
                       const float* __restrict__ pw, const float* __restrict__ pb,
                       const float* __restrict__ f, float* __restrict__ fhat,
                       float* __restrict__ loss, int pn, int k) {
    __shared__ float h_up[CC][HW2];
    __shared__ float hs[CC][169];
    __shared__ float red[4];
    int b = blockIdx.x, coq = blockIdx.y, t = threadIdx.x;
    int nn = pn * pn;
    int y = t >> 4, x = t & 15;

    if (pn == 16) {
        int id = idx[b * HW2 + t];
        const float* er = emb + id * CC;
        #pragma unroll
        for (int c = 0; c < CC; ++c) h_up[c][t] = er[c];
    } else {
        for (int cell = t; cell < nn; cell += 256) {
            int id = idx[b * nn + cell];
            const float* er = emb + id * CC;
            #pragma unroll
            for (int c = 0; c < CC; ++c) hs[c][cell] = er[c];
        }
        __syncthreads();
        float scale = (float)pn / 16.f;
        float sy = (y + 0.5f) * scale - 0.5f;
        sy = fminf(fmaxf(sy, 0.f), (float)(pn - 1));
        int y0 = (int)sy; int y1 = min(y0 + 1, pn - 1); float wy = sy - (float)y0;
        float sx = (x + 0.5f) * scale - 0.5f;
        sx = fminf(fmaxf(sx, 0.f), (float)(pn - 1));
        int x0 = (int)sx; int x1 = min(x0 + 1, pn - 1); float wx = sx - (float)x0;
        float wy0 = 1.f - wy, wx0 = 1.f - wx;
        #pragma unroll
        for (int c = 0; c < CC; ++c) {
            float v00 = hs[c][y0 * pn + x0], v01 = hs[c][y0 * pn + x1];
            float v10 = hs[c][y1 * pn + x0], v11 = hs[c][y1 * pn + x1];
            float a0 = wy0 * v00 + wy * v10;   // contract H first (jax resize order)
            float a1 = wy0 * v01 + wy * v11;
            h_up[c][t] = wx0 * a0 + wx * a1;
        }
    }
    __syncthreads();

    float acc[8];
    #pragma unroll
    for (int o = 0; o < 8; ++o) acc[o] = 0.f;
    for (int ci_ = 0; ci_ < CC; ++ci_) {
        float hv[9];
        #pragma unroll
        for (int dy = 0; dy < 3; ++dy)
            #pragma unroll
            for (int dx = 0; dx < 3; ++dx) {
                int yy = y + dy - 1, xx2 = x + dx - 1;
                hv[dy * 3 + dx] = (yy >= 0 && yy < 16 && xx2 >= 0 && xx2 < 16)
                                  ? h_up[ci_][yy * 16 + xx2] : 0.f;
            }
        const float* wp = pw + ((k * CC + coq * 8) * CC + ci_) * 9;  // uniform -> s_load
        #pragma unroll
        for (int o = 0; o < 8; ++o) {
            const float* w9 = wp + o * (CC * 9);
            #pragma unroll
            for (int q = 0; q < 9; ++q) acc[o] = fmaf(hv[q], w9[q], acc[o]);
        }
    }

    float lsum = 0.f;
    #pragma unroll
    for (int o = 0; o < 8; ++o) {
        int co = coq * 8 + o;
        float hval = h_up[co][t];
        float outv = hval * 0.5f + (acc[o] + pb[k * CC + co]) * 0.5f;
        int pos = (b * CC + co) * HW2 + t;
        float fh = fhat[pos] + outv;
        fhat[pos] = fh;
        float d = fh - f[pos];
        lsum = fmaf(d, d, lsum);
    }
    #pragma unroll
    for (int off = 32; off > 0; off >>= 1) lsum += __shfl_down(lsum, off, 64);
    if ((t & 63) == 0) red[t >> 6] = lsum;
    __syncthreads();
    if (t == 0) atomicAdd(loss, red[0] + red[1] + red[2] + red[3]);
}

// ---------------- writeout: f32 -> out dtype (matches probed input dtype) ----------------
__global__ void k_out(const float* __restrict__ fhat, const float* __restrict__ loss,
                      const int* __restrict__ flag, void* __restrict__ out) {
    bool isf32 = (*flag != 0);
    int i = blockIdx.x * 256 + threadIdx.x;
    if (i > NELEM) return;
    float v;
    if (i < NELEM) v = fhat[i];
    else           v = (*loss) * (1.25f / (float)NELEM / 8.f);
    if (isf32) ((float*)out)[i] = v;
    else       ((__hip_bfloat16*)out)[i] = __float2bfloat16(v);
}

extern "C" void kernel_launch(void* const* d_in, const int* in_sizes, int n_in,
                              void* d_out, int out_size, void* d_ws, size_t ws_size,
                              hipStream_t stream) {
    const void* fin  = d_in[0];
    const void* ein  = d_in[1];
    const void* win  = d_in[2];
    const void* bin_ = d_in[3];
    float* ws = (float*)d_ws;
    float* f    = ws + OFF_F;
    float* fhat = ws + OFF_FHAT;
    float* emb  = ws + OFF_EMB;
    float* esq  = ws + OFF_ESQ;
    float* pw   = ws + OFF_PW;
    float* pb   = ws + OFF_PB;
    float* rest = ws + OFF_REST;
    float* cd   = ws + OFF_CD;
    int*   ci   = (int*)(ws + OFF_CI);
    int*   idx  = (int*)(ws + OFF_IDX);
    float* loss = ws + OFF_LOSS;
    int*   flag = (int*)(ws + OFF_FLAG);

    static const int PN[8] = {1, 2, 4, 6, 8, 10, 13, 16};
    static const int KK[8] = {0, 0, 1, 1, 2, 2, 3, 3};
    static const int SP[8] = {256, 128, 32, 16, 8, 8, 4, 4};

    k_probe<<<1, 256, 0, stream>>>(fin, flag);
    k_prep<<<(NELEM + 255) / 256, 256, 0, stream>>>(fin, ein, win, bin_, flag, f, fhat, emb, pw, pb, loss);
    k_esq<<<(VV + 255) / 256, 256, 0, stream>>>(emb, esq);

    for (int si = 0; si < 8; ++si) {
        int pn = PN[si];
        int Ntot = BB * pn * pn;
        int Sp = SP[si];
        int cpw = VV / Sp;
        k_pool<<<(Ntot * CC + 255) / 256, 256, 0, stream>>>(f, fhat, rest, pn);
        k_argmin1<<<dim3(Ntot / 64, Sp), 64, 0, stream>>>(rest, emb, esq, cd, ci, Ntot, cpw);
        k_argmin2<<<(Ntot + 255) / 256, 256, 0, stream>>>(cd, ci, idx, Ntot, Sp);
        k_fuse<<<dim3(BB, 4), 256, 0, stream>>>(emb, idx, pw, pb, f, fhat, loss, pn, KK[si]);
    }
    k_out<<<(NELEM + 1 + 255) / 256, 256, 0, stream>>>(fhat, loss, flag, d_out);
}

// Round 3
// 660.789 us; speedup vs baseline: 1.7305x; 1.7305x over previous
//
#include <hip/hip_runtime.h>
#include <hip/hip_bf16.h>

#define BB 64
#define CC 32
#define HW2 256   // 16*16
#define VV 4096
#define NELEM (BB*CC*HW2)   // 524288
#define NPAD 16640          // padded vector-count stride for rest_t (>= 16384, mult of 256)

// ---------------- workspace layout (float offsets) ----------------
#define OFF_F    0
#define OFF_FHAT (OFF_F    + NELEM)        // 524288
#define OFF_EMB  (OFF_FHAT + NELEM)        // 1048576
#define OFF_ESQ  (OFF_EMB  + VV*CC)        // 1179648
#define OFF_PW   (OFF_ESQ  + VV)           // 1183744
#define OFF_PB   (OFF_PW   + 4*CC*CC*9)    // 1220608
#define OFF_REST (OFF_PB   + 4*CC)         // 1220736  (32*NPAD = 532480 floats)
#define OFF_BEST (OFF_REST + CC*NPAD)      // 1753216  (NPAD u64 = 33280 floats; byte-off /8 ok)
#define OFF_LOSS (OFF_BEST + 2*NPAD)       // 1786496
#define OFF_FLAG (OFF_LOSS + 1)            // 1786497

// ---------------- dtype probe: is input 0 f32 (1) or bf16 (0)? ----------------
__global__ void k_probe(const void* __restrict__ fin, int* __restrict__ flag) {
    __shared__ int cnt[256];
    int t = threadIdx.x;
    const __hip_bfloat16* p = (const __hip_bfloat16*)fin;
    int local = 0;
    for (int i = t; i < 8192; i += 256) {
        float v = __bfloat162float(p[i]);
        if (!(fabsf(v) < 1e3f)) local++;   // also true for NaN
    }
    cnt[t] = local;
    __syncthreads();
    for (int s = 128; s > 0; s >>= 1) {
        if (t < s) cnt[t] += cnt[t + s];
        __syncthreads();
    }
    if (t == 0) *flag = (cnt[0] >= 64) ? 1 : 0;   // 1 => inputs are f32
}

// ---------------- prep: decode -> f32 ws, zero f_hat & loss ----------------
__global__ void k_prep(const void* __restrict__ fin,
                       const void* __restrict__ ein,
                       const void* __restrict__ win,
                       const void* __restrict__ bin_,
                       const int* __restrict__ flag,
                       float* __restrict__ f, float* __restrict__ fhat,
                       float* __restrict__ emb, float* __restrict__ pw,
                       float* __restrict__ pb, float* __restrict__ loss) {
    bool isf32 = (*flag != 0);
    int i = blockIdx.x * 256 + threadIdx.x;
    if (i < NELEM) {
        f[i] = isf32 ? ((const float*)fin)[i]
                     : __bfloat162float(((const __hip_bfloat16*)fin)[i]);
        fhat[i] = 0.f;
    }
    if (i < VV*CC)
        emb[i] = isf32 ? ((const float*)ein)[i]
                       : __bfloat162float(((const __hip_bfloat16*)ein)[i]);
    if (i < 4*CC*CC*9)
        pw[i] = isf32 ? ((const float*)win)[i]
                      : __bfloat162float(((const __hip_bfloat16*)win)[i]);
    if (i < 4*CC)
        pb[i] = isf32 ? ((const float*)bin_)[i]
                      : __bfloat162float(((const __hip_bfloat16*)bin_)[i]);
    if (i == 0) *loss = 0.f;
}

__global__ void k_esq(const float* __restrict__ emb, float* __restrict__ esq) {
    int v = blockIdx.x * 256 + threadIdx.x;
    if (v >= VV) return;
    const float* e = emb + v * CC;
    float s = 0.f;
    #pragma unroll
    for (int c = 0; c < CC; ++c) s = fmaf(e[c], e[c], s);
    esq[v] = s;
}

// ---------------- adaptive avg pool of (f - f_hat) -> rest_t[c][n] (transposed) ------
// grid = (ceil(Ntot/256), 32); also re-inits best[] for this scale (c==0 plane).
__global__ void k_pool(const float* __restrict__ f, const float* __restrict__ fhat,
                       float* __restrict__ rest_t, unsigned long long* __restrict__ best,
                       int pn) {
    int n = blockIdx.x * 256 + threadIdx.x;
    int c = blockIdx.y;
    int nn = pn * pn;
    int Ntot = BB * nn;
    if (n >= Ntot) return;
    if (c == 0) best[n] = 0xFFFFFFFFFFFFFFFFull;
    int cell = n % nn, b = n / nn;
    int i = cell / pn, j = cell % pn;
    int s0 = (i * 16) / pn, e0 = ((i + 1) * 16 + pn - 1) / pn;
    int s1 = (j * 16) / pn, e1 = ((j + 1) * 16 + pn - 1) / pn;
    float inv = 1.f / (float)((e0 - s0) * (e1 - s1));
    const float* fb = f + (b * CC + c) * HW2;
    const float* hb = fhat + (b * CC + c) * HW2;
    float s = 0.f;
    for (int h = s0; h < e0; ++h)
        for (int w = s1; w < e1; ++w)
            s += fb[h * 16 + w] - hb[h * 16 + w];
    rest_t[c * NPAD + n] = s * inv;
}

// ---------------- argmin: thread=vector (coalesced x), wave-uniform code loop --------
// grid = (ceil(Ntot/256), Sp). Per-slice best folded into packed u64 atomicMin:
// (monotonic(dist) << 32) | code -> exact f32 order, ties -> smaller code (numpy argmin).
__global__ __launch_bounds__(256, 4)
void k_argmin1(const float* __restrict__ rest_t, const float* __restrict__ emb,
               const float* __restrict__ esq, unsigned long long* __restrict__ best,
               int Ntot, int cpw) {
    int n = blockIdx.x * 256 + threadIdx.x;
    int v0 = blockIdx.y * cpw;
    bool valid = (n < Ntot);
    int nc = valid ? n : 0;
    float x[CC];
    #pragma unroll
    for (int c = 0; c < CC; ++c) x[c] = rest_t[c * NPAD + nc];   // coalesced
    float xx = 0.f;
    #pragma unroll
    for (int c = 0; c < CC; ++c) xx = fmaf(x[c], x[c], xx);
    float bd = 3.4e38f;
    int bi = v0;
    #pragma unroll 2
    for (int v = v0; v < v0 + cpw; ++v) {
        const float* e = emb + v * CC;   // wave-uniform -> s_load
        float d0 = 0.f, d1 = 0.f, d2 = 0.f, d3 = 0.f;
        #pragma unroll
        for (int c = 0; c < CC; c += 4) {
            d0 = fmaf(x[c],   e[c],   d0);
            d1 = fmaf(x[c+1], e[c+1], d1);
            d2 = fmaf(x[c+2], e[c+2], d2);
            d3 = fmaf(x[c+3], e[c+3], d3);
        }
        float dist = (xx + esq[v]) - 2.f * ((d0 + d1) + (d2 + d3));
        if (dist < bd) { bd = dist; bi = v; }
    }
    if (valid) {
        unsigned u = __float_as_uint(bd);
        unsigned long long mono = (u & 0x80000000u)
            ? (unsigned long long)(~u)
            : (unsigned long long)(u | 0x80000000u);
        atomicMin(best + n, (mono << 32) | (unsigned long long)(unsigned)bi);
    }
}

// ---------------- fused: gather + bilinear upsample + conv3x3(phi) + f_hat += + loss ----
__global__ void k_fuse(const float* __restrict__ emb,
                       const unsigned long long* __restrict__ best,
                       const float* __restrict__ pw, const float* __restrict__ pb,
                       const float* __restrict__ f, float* __restrict__ fhat,
                       float* __restrict__ loss, int pn, int k) {
    __shared__ float h_up[CC][HW2];
    __shared__ float hs[CC][169];
    __shared__ float red[4];
    int b = blockIdx.x, coq = blockIdx.y, t = threadIdx.x;
    int nn = pn * pn;
    int y = t >> 4, x = t & 15;

    if (pn == 16) {
        int id = (int)(unsigned)(best[b * HW2 + t] & 0xFFFFFFFFull);
        const float* er = emb + id * CC;
        #pragma unroll
        for (int c = 0; c < CC; ++c) h_up[c][t] = er[c];
    } else {
        for (int cell = t; cell < nn; cell += 256) {
            int id = (int)(unsigned)(best[b * nn + cell] & 0xFFFFFFFFull);
            const float* er = emb + id * CC;
            #pragma unroll
            for (int c = 0; c < CC; ++c) hs[c][cell] = er[c];
        }
        __syncthreads();
        float scale = (float)pn / 16.f;
        float sy = (y + 0.5f) * scale - 0.5f;
        sy = fminf(fmaxf(sy, 0.f), (float)(pn - 1));
        int y0 = (int)sy; int y1 = min(y0 + 1, pn - 1); float wy = sy - (float)y0;
        float sx = (x + 0.5f) * scale - 0.5f;
        sx = fminf(fmaxf(sx, 0.f), (float)(pn - 1));
        int x0 = (int)sx; int x1 = min(x0 + 1, pn - 1); float wx = sx - (float)x0;
        float wy0 = 1.f - wy, wx0 = 1.f - wx;
        #pragma unroll
        for (int c = 0; c < CC; ++c) {
            float v00 = hs[c][y0 * pn + x0], v01 = hs[c][y0 * pn + x1];
            float v10 = hs[c][y1 * pn + x0], v11 = hs[c][y1 * pn + x1];
            float a0 = wy0 * v00 + wy * v10;   // contract H first (jax resize order)
            float a1 = wy0 * v01 + wy * v11;
            h_up[c][t] = wx0 * a0 + wx * a1;
        }
    }
    __syncthreads();

    float acc[8];
    #pragma unroll
    for (int o = 0; o < 8; ++o) acc[o] = 0.f;
    for (int ci_ = 0; ci_ < CC; ++ci_) {
        float hv[9];
        #pragma unroll
        for (int dy = 0; dy < 3; ++dy)
            #pragma unroll
            for (int dx = 0; dx < 3; ++dx) {
                int yy = y + dy - 1, xx2 = x + dx - 1;
                hv[dy * 3 + dx] = (yy >= 0 && yy < 16 && xx2 >= 0 && xx2 < 16)
                                  ? h_up[ci_][yy * 16 + xx2] : 0.f;
            }
        const float* wp = pw + ((k * CC + coq * 8) * CC + ci_) * 9;  // uniform -> s_load
        #pragma unroll
        for (int o = 0; o < 8; ++o) {
            const float* w9 = wp + o * (CC * 9);
            #pragma unroll
            for (int q = 0; q < 9; ++q) acc[o] = fmaf(hv[q], w9[q], acc[o]);
        }
    }

    float lsum = 0.f;
    #pragma unroll
    for (int o = 0; o < 8; ++o) {
        int co = coq * 8 + o;
        float hval = h_up[co][t];
        float outv = hval * 0.5f + (acc[o] + pb[k * CC + co]) * 0.5f;
        int pos = (b * CC + co) * HW2 + t;
        float fh = fhat[pos] + outv;
        fhat[pos] = fh;
        float d = fh - f[pos];
        lsum = fmaf(d, d, lsum);
    }
    #pragma unroll
    for (int off = 32; off > 0; off >>= 1) lsum += __shfl_down(lsum, off, 64);
    if ((t & 63) == 0) red[t >> 6] = lsum;
    __syncthreads();
    if (t == 0) atomicAdd(loss, red[0] + red[1] + red[2] + red[3]);
}

// ---------------- writeout: f32 -> out dtype (matches probed input dtype) ----------------
__global__ void k_out(const float* __restrict__ fhat, const float* __restrict__ loss,
                      const int* __restrict__ flag, void* __restrict__ out) {
    bool isf32 = (*flag != 0);
    int i = blockIdx.x * 256 + threadIdx.x;
    if (i > NELEM) return;
    float v;
    if (i < NELEM) v = fhat[i];
    else           v = (*loss) * (1.25f / (float)NELEM / 8.f);
    if (isf32) ((float*)out)[i] = v;
    else       ((__hip_bfloat16*)out)[i] = __float2bfloat16(v);
}

extern "C" void kernel_launch(void* const* d_in, const int* in_sizes, int n_in,
                              void* d_out, int out_size, void* d_ws, size_t ws_size,
                              hipStream_t stream) {
    const void* fin  = d_in[0];
    const void* ein  = d_in[1];
    const void* win  = d_in[2];
    const void* bin_ = d_in[3];
    float* ws = (float*)d_ws;
    float* f    = ws + OFF_F;
    float* fhat = ws + OFF_FHAT;
    float* emb  = ws + OFF_EMB;
    float* esq  = ws + OFF_ESQ;
    float* pw   = ws + OFF_PW;
    float* pb   = ws + OFF_PB;
    float* rest_t = ws + OFF_REST;
    unsigned long long* best = (unsigned long long*)(ws + OFF_BEST);
    float* loss = ws + OFF_LOSS;
    int*   flag = (int*)(ws + OFF_FLAG);

    static const int PN[8] = {1, 2, 4, 6, 8, 10, 13, 16};
    static const int KK[8] = {0, 0, 1, 1, 2, 2, 3, 3};
    static const int SP[8] = {64, 64, 32, 32, 32, 16, 16, 16};

    k_probe<<<1, 256, 0, stream>>>(fin, flag);
    k_prep<<<(NELEM + 255) / 256, 256, 0, stream>>>(fin, ein, win, bin_, flag, f, fhat, emb, pw, pb, loss);
    k_esq<<<(VV + 255) / 256, 256, 0, stream>>>(emb, esq);

    for (int si = 0; si < 8; ++si) {
        int pn = PN[si];
        int Ntot = BB * pn * pn;
        int Sp = SP[si];
        int cpw = VV / Sp;
        int gx = (Ntot + 255) / 256;
        k_pool<<<dim3(gx, CC), 256, 0, stream>>>(f, fhat, rest_t, best, pn);
        k_argmin1<<<dim3(gx, Sp), 256, 0, stream>>>(rest_t, emb, esq, best, Ntot, cpw);
        k_fuse<<<dim3(BB, 4), 256, 0, stream>>>(emb, best, pw, pb, f, fhat, loss, pn, KK[si]);
    }
    k_out<<<(NELEM + 1 + 255) / 256, 256, 0, stream>>>(fhat, loss, flag, d_out);
}

// Round 4
// 524.286 us; speedup vs baseline: 2.1811x; 1.2604x over previous
//
#include <hip/hip_runtime.h>
#include <hip/hip_bf16.h>

#define BB 64
#define CC 32
#define HW2 256   // 16*16
#define VV 4096
#define NELEM (BB*CC*HW2)   // 524288
#define NPAD 16640          // padded vector-count stride for rest_t

// ---------------- workspace layout (float offsets) ----------------
#define OFF_F     0
#define OFF_FHAT  (OFF_F     + NELEM)        // 524288
#define OFF_EMB   (OFF_FHAT  + NELEM)        // 1048576
#define OFF_ESQ   (OFF_EMB   + VV*CC)        // 1179648
#define OFF_PW    (OFF_ESQ   + VV)           // 1183744
#define OFF_PB    (OFF_PW    + 4*CC*CC*9)    // 1220608
#define OFF_REST  (OFF_PB    + 4*CC)         // 1220736  (32*NPAD floats)
#define OFF_BESTA (OFF_REST  + CC*NPAD)      // 1753216  (NPAD u64)
#define OFF_BESTB (OFF_BESTA + 2*NPAD)       // 1786496  (NPAD u64)
#define OFF_LOSS  (OFF_BESTB + 2*NPAD)       // 1819776
#define OFF_FLAG  (OFF_LOSS  + 1)

// ---------------- dtype probe: is input 0 f32 (1) or bf16 (0)? ----------------
__global__ void k_probe(const void* __restrict__ fin, int* __restrict__ flag) {
    __shared__ int cnt[256];
    int t = threadIdx.x;
    const __hip_bfloat16* p = (const __hip_bfloat16*)fin;
    int local = 0;
    for (int i = t; i < 8192; i += 256) {
        float v = __bfloat162float(p[i]);
        if (!(fabsf(v) < 1e3f)) local++;   // also true for NaN
    }
    cnt[t] = local;
    __syncthreads();
    for (int s = 128; s > 0; s >>= 1) {
        if (t < s) cnt[t] += cnt[t + s];
        __syncthreads();
    }
    if (t == 0) *flag = (cnt[0] >= 64) ? 1 : 0;
}

// ---------------- prep: decode -> f32 ws, zero f_hat & loss ----------------
__global__ void k_prep(const void* __restrict__ fin,
                       const void* __restrict__ ein,
                       const void* __restrict__ win,
                       const void* __restrict__ bin_,
                       const int* __restrict__ flag,
                       float* __restrict__ f, float* __restrict__ fhat,
                       float* __restrict__ emb, float* __restrict__ pw,
                       float* __restrict__ pb, float* __restrict__ loss) {
    bool isf32 = (*flag != 0);
    int i = blockIdx.x * 256 + threadIdx.x;
    if (i < NELEM) {
        f[i] = isf32 ? ((const float*)fin)[i]
                     : __bfloat162float(((const __hip_bfloat16*)fin)[i]);
        fhat[i] = 0.f;
    }
    if (i < VV*CC)
        emb[i] = isf32 ? ((const float*)ein)[i]
                       : __bfloat162float(((const __hip_bfloat16*)ein)[i]);
    if (i < 4*CC*CC*9)
        pw[i] = isf32 ? ((const float*)win)[i]
                      : __bfloat162float(((const __hip_bfloat16*)win)[i]);
    if (i < 4*CC)
        pb[i] = isf32 ? ((const float*)bin_)[i]
                      : __bfloat162float(((const __hip_bfloat16*)bin_)[i]);
    if (i == 0) *loss = 0.f;
}

__global__ void k_esq(const float* __restrict__ emb, float* __restrict__ esq) {
    int v = blockIdx.x * 256 + threadIdx.x;
    if (v >= VV) return;
    const float* e = emb + v * CC;
    float s = 0.f;
    #pragma unroll
    for (int c = 0; c < CC; ++c) s = fmaf(e[c], e[c], s);
    esq[v] = s;
}

// ---------------- pool for scale 0 only (pn=1), also init bestA --------------
__global__ void k_pool0(const float* __restrict__ f, const float* __restrict__ fhat,
                        float* __restrict__ rest_t, unsigned long long* __restrict__ best) {
    int n = threadIdx.x;     // grid (1, 32)
    int c = blockIdx.y;
    if (n >= BB) return;
    if (c == 0) best[n] = 0xFFFFFFFFFFFFFFFFull;
    const float* fb = f + (n * CC + c) * HW2;
    const float* hb = fhat + (n * CC + c) * HW2;
    float s = 0.f;
    for (int h = 0; h < 16; ++h)
        for (int w = 0; w < 16; ++w)
            s += fb[h * 16 + w] - hb[h * 16 + w];
    rest_t[c * NPAD + n] = s * (1.f / 256.f);
}

// ---------------- argmin: VPT vectors/thread, wave-uniform code loop ----------
// best merge: packed u64 atomicMin (monotonic(dist)<<32 | code) -> exact f32
// order, ties -> smaller code index (numpy argmin semantics).
template<int VPT>
__global__ __launch_bounds__(256, 4)
void k_argmin1(const float* __restrict__ rest_t, const float* __restrict__ emb,
               const float* __restrict__ esq, unsigned long long* __restrict__ best,
               int Ntot, int cpw) {
    int tid = threadIdx.x;
    int base = blockIdx.x * (256 * VPT) + tid;
    int v0 = blockIdx.y * cpw;
    float x[VPT][CC];
    bool valid[VPT];
    int nidx[VPT];
    #pragma unroll
    for (int p = 0; p < VPT; ++p) {
        int n = base + p * 256;
        nidx[p] = n;
        valid[p] = (n < Ntot);
        int nc = valid[p] ? n : 0;
        #pragma unroll
        for (int c = 0; c < CC; ++c) x[p][c] = rest_t[c * NPAD + nc];   // coalesced
    }
    // pin the query in VGPRs: values become opaque -> no rematerialization
    #pragma unroll
    for (int p = 0; p < VPT; ++p)
        #pragma unroll
        for (int c = 0; c < CC; ++c)
            asm volatile("" : "+v"(x[p][c]));
    float xx[VPT];
    #pragma unroll
    for (int p = 0; p < VPT; ++p) {
        float s = 0.f;
        #pragma unroll
        for (int c = 0; c < CC; ++c) s = fmaf(x[p][c], x[p][c], s);
        xx[p] = s;
    }
    float bd[VPT];
    int bi[VPT];
    #pragma unroll
    for (int p = 0; p < VPT; ++p) { bd[p] = 3.4e38f; bi[p] = v0; }

    #pragma unroll 2
    for (int v = v0; v < v0 + cpw; ++v) {
        const float* e = emb + v * CC;   // wave-uniform -> s_load
        float d0[VPT], d1[VPT], d2[VPT], d3[VPT];
        #pragma unroll
        for (int p = 0; p < VPT; ++p) { d0[p]=0.f; d1[p]=0.f; d2[p]=0.f; d3[p]=0.f; }
        #pragma unroll
        for (int c = 0; c < CC; c += 4) {
            float e0 = e[c], e1 = e[c+1], e2 = e[c+2], e3 = e[c+3];
            #pragma unroll
            for (int p = 0; p < VPT; ++p) {
                d0[p] = fmaf(x[p][c],   e0, d0[p]);
                d1[p] = fmaf(x[p][c+1], e1, d1[p]);
                d2[p] = fmaf(x[p][c+2], e2, d2[p]);
                d3[p] = fmaf(x[p][c+3], e3, d3[p]);
            }
        }
        float ev = esq[v];
        #pragma unroll
        for (int p = 0; p < VPT; ++p) {
            float dist = (xx[p] + ev) - 2.f * ((d0[p] + d1[p]) + (d2[p] + d3[p]));
            if (dist < bd[p]) { bd[p] = dist; bi[p] = v; }
        }
    }
    #pragma unroll
    for (int p = 0; p < VPT; ++p) {
        if (valid[p]) {
            unsigned u = __float_as_uint(bd[p]);
            unsigned long long mono = (u & 0x80000000u)
                ? (unsigned long long)(~u)
                : (unsigned long long)(u | 0x80000000u);
            atomicMin(best + nidx[p], (mono << 32) | (unsigned long long)(unsigned)bi[p]);
        }
    }
}

// ---------------- fused: gather + upsample + conv3x3(phi) + f_hat + loss
//                  + pool(next scale) + best-init(next scale) ------------------
__global__ __launch_bounds__(256)
void k_fuse(const float* __restrict__ emb,
            const unsigned long long* __restrict__ best,
            const float* __restrict__ pw, const float* __restrict__ pb,
            const float* __restrict__ f, float* __restrict__ fhat,
            float* __restrict__ loss,
            float* __restrict__ rest_t,
            unsigned long long* __restrict__ best_next,
            int pn, int k, int pn_next) {
    __shared__ float h_up[CC][HW2];
    __shared__ float extra[CC * 169];   // hs during upsample, then diff[8][256]
    __shared__ float red[4];
    int b = blockIdx.x, coq = blockIdx.y, t = threadIdx.x;
    int nn = pn * pn;
    int y = t >> 4, x = t & 15;

    if (pn == 16) {
        int id = (int)(unsigned)(best[b * HW2 + t] & 0xFFFFFFFFull);
        const float* er = emb + id * CC;
        #pragma unroll
        for (int c = 0; c < CC; ++c) h_up[c][t] = er[c];
    } else {
        float (*hs)[169] = (float(*)[169])extra;
        for (int cell = t; cell < nn; cell += 256) {
            int id = (int)(unsigned)(best[b * nn + cell] & 0xFFFFFFFFull);
            const float* er = emb + id * CC;
            #pragma unroll
            for (int c = 0; c < CC; ++c) hs[c][cell] = er[c];
        }
        __syncthreads();
        float scale = (float)pn / 16.f;
        float sy = (y + 0.5f) * scale - 0.5f;
        sy = fminf(fmaxf(sy, 0.f), (float)(pn - 1));
        int y0 = (int)sy; int y1 = min(y0 + 1, pn - 1); float wy = sy - (float)y0;
        float sx = (x + 0.5f) * scale - 0.5f;
        sx = fminf(fmaxf(sx, 0.f), (float)(pn - 1));
        int x0 = (int)sx; int x1 = min(x0 + 1, pn - 1); float wx = sx - (float)x0;
        float wy0 = 1.f - wy, wx0 = 1.f - wx;
        #pragma unroll
        for (int c = 0; c < CC; ++c) {
            float v00 = hs[c][y0 * pn + x0], v01 = hs[c][y0 * pn + x1];
            float v10 = hs[c][y1 * pn + x0], v11 = hs[c][y1 * pn + x1];
            float a0 = wy0 * v00 + wy * v10;   // contract H first (jax resize order)
            float a1 = wy0 * v01 + wy * v11;
            h_up[c][t] = wx0 * a0 + wx * a1;
        }
    }
    __syncthreads();   // h_up ready; all reads of hs/extra done

    float acc[8];
    #pragma unroll
    for (int o = 0; o < 8; ++o) acc[o] = 0.f;
    for (int ci_ = 0; ci_ < CC; ++ci_) {
        float hv[9];
        #pragma unroll
        for (int dy = 0; dy < 3; ++dy)
            #pragma unroll
            for (int dx = 0; dx < 3; ++dx) {
                int yy = y + dy - 1, xx2 = x + dx - 1;
                hv[dy * 3 + dx] = (yy >= 0 && yy < 16 && xx2 >= 0 && xx2 < 16)
                                  ? h_up[ci_][yy * 16 + xx2] : 0.f;
            }
        const float* wp = pw + ((k * CC + coq * 8) * CC + ci_) * 9;  // uniform -> s_load
        #pragma unroll
        for (int o = 0; o < 8; ++o) {
            const float* w9 = wp + o * (CC * 9);
            #pragma unroll
            for (int q = 0; q < 9; ++q) acc[o] = fmaf(hv[q], w9[q], acc[o]);
        }
    }

    float* diff = extra;   // [8][256], safe: hs reads completed before prior barrier
    float lsum = 0.f;
    #pragma unroll
    for (int o = 0; o < 8; ++o) {
        int co = coq * 8 + o;
        float hval = h_up[co][t];
        float outv = hval * 0.5f + (acc[o] + pb[k * CC + co]) * 0.5f;
        int pos = (b * CC + co) * HW2 + t;
        float fh = fhat[pos] + outv;
        fhat[pos] = fh;
        float dd = f[pos] - fh;        // = (f - fhat_new), used for loss AND pooling
        diff[o * HW2 + t] = dd;
        lsum = fmaf(dd, dd, lsum);
    }
    #pragma unroll
    for (int off = 32; off > 0; off >>= 1) lsum += __shfl_down(lsum, off, 64);
    if ((t & 63) == 0) red[t >> 6] = lsum;
    __syncthreads();   // red + diff visible
    if (t == 0) atomicAdd(loss, red[0] + red[1] + red[2] + red[3]);

    if (pn_next > 0) {
        int nn2 = pn_next * pn_next;
        for (int q = t; q < nn2 * 8; q += 256) {
            int cell = q % nn2, o = q / nn2;
            int i = cell / pn_next, j = cell % pn_next;
            int s0 = (i * 16) / pn_next, e0 = ((i + 1) * 16 + pn_next - 1) / pn_next;
            int s1 = (j * 16) / pn_next, e1 = ((j + 1) * 16 + pn_next - 1) / pn_next;
            float inv = 1.f / (float)((e0 - s0) * (e1 - s1));
            float s = 0.f;
            for (int h = s0; h < e0; ++h)
                for (int w = s1; w < e1; ++w)
                    s += diff[o * HW2 + h * 16 + w];
            rest_t[(coq * 8 + o) * NPAD + b * nn2 + cell] = s * inv;
        }
        if (coq == 0)
            for (int q = t; q < nn2; q += 256)
                best_next[b * nn2 + q] = 0xFFFFFFFFFFFFFFFFull;
    }
}

// ---------------- writeout: f32 -> out dtype (matches probed input dtype) ----------------
__global__ void k_out(const float* __restrict__ fhat, const float* __restrict__ loss,
                      const int* __restrict__ flag, void* __restrict__ out) {
    bool isf32 = (*flag != 0);
    int i = blockIdx.x * 256 + threadIdx.x;
    if (i > NELEM) return;
    float v;
    if (i < NELEM) v = fhat[i];
    else           v = (*loss) * (1.25f / (float)NELEM / 8.f);
    if (isf32) ((float*)out)[i] = v;
    else       ((__hip_bfloat16*)out)[i] = __float2bfloat16(v);
}

extern "C" void kernel_launch(void* const* d_in, const int* in_sizes, int n_in,
                              void* d_out, int out_size, void* d_ws, size_t ws_size,
                              hipStream_t stream) {
    const void* fin  = d_in[0];
    const void* ein  = d_in[1];
    const void* win  = d_in[2];
    const void* bin_ = d_in[3];
    float* ws = (float*)d_ws;
    float* f    = ws + OFF_F;
    float* fhat = ws + OFF_FHAT;
    float* emb  = ws + OFF_EMB;
    float* esq  = ws + OFF_ESQ;
    float* pw   = ws + OFF_PW;
    float* pb   = ws + OFF_PB;
    float* rest_t = ws + OFF_REST;
    unsigned long long* bestA = (unsigned long long*)(ws + OFF_BESTA);
    unsigned long long* bestB = (unsigned long long*)(ws + OFF_BESTB);
    float* loss = ws + OFF_LOSS;
    int*   flag = (int*)(ws + OFF_FLAG);

    static const int PN[8]  = {1, 2, 4, 6, 8, 10, 13, 16};
    static const int KK[8]  = {0, 0, 1, 1, 2, 2, 3, 3};
    static const int SP[8]  = {64, 64, 64, 64, 64, 32, 32, 32};
    static const int VPT[8] = {1, 1, 1, 1, 2, 2, 2, 2};

    k_probe<<<1, 256, 0, stream>>>(fin, flag);
    k_prep<<<(NELEM + 255) / 256, 256, 0, stream>>>(fin, ein, win, bin_, flag, f, fhat, emb, pw, pb, loss);
    k_esq<<<(VV + 255) / 256, 256, 0, stream>>>(emb, esq);
    k_pool0<<<dim3(1, CC), 256, 0, stream>>>(f, fhat, rest_t, bestA);

    for (int si = 0; si < 8; ++si) {
        int pn = PN[si];
        int Ntot = BB * pn * pn;
        int Sp = SP[si];
        int cpw = VV / Sp;
        unsigned long long* bcur = (si & 1) ? bestB : bestA;
        unsigned long long* bnxt = (si & 1) ? bestA : bestB;
        int pn_next = (si < 7) ? PN[si + 1] : 0;
        if (VPT[si] == 2) {
            int gx = (Ntot + 511) / 512;
            k_argmin1<2><<<dim3(gx, Sp), 256, 0, stream>>>(rest_t, emb, esq, bcur, Ntot, cpw);
        } else {
            int gx = (Ntot + 255) / 256;
            k_argmin1<1><<<dim3(gx, Sp), 256, 0, stream>>>(rest_t, emb, esq, bcur, Ntot, cpw);
        }
        k_fuse<<<dim3(BB, 4), 256, 0, stream>>>(emb, bcur, pw, pb, f, fhat, loss,
                                                rest_t, bnxt, pn, KK[si], pn_next);
    }
    k_out<<<(NELEM + 1 + 255) / 256, 256, 0, stream>>>(fhat, loss, flag, d_out);
}

// Round 5
// 516.926 us; speedup vs baseline: 2.2122x; 1.0142x over previous
//
#include <hip/hip_runtime.h>
#include <hip/hip_bf16.h>

#define BB 64
#define CC 32
#define HW2 256   // 16*16
#define VV 4096
#define NELEM (BB*CC*HW2)   // 524288
#define NPAD 16640          // padded vector-count stride for rest_t

// ---------------- workspace layout (float offsets) ----------------
#define OFF_F     0
#define OFF_FHAT  (OFF_F     + NELEM)        // 524288
#define OFF_EMB   (OFF_FHAT  + NELEM)        // 1048576
#define OFF_ESQ   (OFF_EMB   + VV*CC)        // 1179648
#define OFF_PW    (OFF_ESQ   + VV)           // 1183744
#define OFF_PB    (OFF_PW    + 4*CC*CC*9)    // 1220608
#define OFF_REST  (OFF_PB    + 4*CC)         // 1220736  (32*NPAD floats)
#define OFF_BESTA (OFF_REST  + CC*NPAD)      // 1753216  (NPAD u64)
#define OFF_BESTB (OFF_BESTA + 2*NPAD)       // 1786496  (NPAD u64)
#define OFF_LOSS  (OFF_BESTB + 2*NPAD)       // 1819776
#define OFF_FLAG  (OFF_LOSS  + 1)

// ---------------- dtype probe: is input 0 f32 (1) or bf16 (0)? ----------------
__global__ void k_probe(const void* __restrict__ fin, int* __restrict__ flag) {
    __shared__ int cnt[256];
    int t = threadIdx.x;
    const __hip_bfloat16* p = (const __hip_bfloat16*)fin;
    int local = 0;
    for (int i = t; i < 8192; i += 256) {
        float v = __bfloat162float(p[i]);
        if (!(fabsf(v) < 1e3f)) local++;   // also true for NaN
    }
    cnt[t] = local;
    __syncthreads();
    for (int s = 128; s > 0; s >>= 1) {
        if (t < s) cnt[t] += cnt[t + s];
        __syncthreads();
    }
    if (t == 0) *flag = (cnt[0] >= 64) ? 1 : 0;
}

// ---------------- prep: decode -> f32 ws, zero f_hat & loss ----------------
__global__ void k_prep(const void* __restrict__ fin,
                       const void* __restrict__ ein,
                       const void* __restrict__ win,
                       const void* __restrict__ bin_,
                       const int* __restrict__ flag,
                       float* __restrict__ f, float* __restrict__ fhat,
                       float* __restrict__ emb, float* __restrict__ pw,
                       float* __restrict__ pb, float* __restrict__ loss) {
    bool isf32 = (*flag != 0);
    int i = blockIdx.x * 256 + threadIdx.x;
    if (i < NELEM) {
        f[i] = isf32 ? ((const float*)fin)[i]
                     : __bfloat162float(((const __hip_bfloat16*)fin)[i]);
        fhat[i] = 0.f;
    }
    if (i < VV*CC)
        emb[i] = isf32 ? ((const float*)ein)[i]
                       : __bfloat162float(((const __hip_bfloat16*)ein)[i]);
    if (i < 4*CC*CC*9)
        pw[i] = isf32 ? ((const float*)win)[i]
                      : __bfloat162float(((const __hip_bfloat16*)win)[i]);
    if (i < 4*CC)
        pb[i] = isf32 ? ((const float*)bin_)[i]
                      : __bfloat162float(((const __hip_bfloat16*)bin_)[i]);
    if (i == 0) *loss = 0.f;
}

__global__ void k_esq(const float* __restrict__ emb, float* __restrict__ esq) {
    int v = blockIdx.x * 256 + threadIdx.x;
    if (v >= VV) return;
    const float* e = emb + v * CC;
    float s = 0.f;
    #pragma unroll
    for (int c = 0; c < CC; ++c) s = fmaf(e[c], e[c], s);
    esq[v] = s;
}

// ---------------- pool for scale 0 only (pn=1), also init bestA --------------
__global__ void k_pool0(const float* __restrict__ f, const float* __restrict__ fhat,
                        float* __restrict__ rest_t, unsigned long long* __restrict__ best) {
    int n = threadIdx.x;     // grid (1, 32)
    int c = blockIdx.y;
    if (n >= BB) return;
    if (c == 0) best[n] = 0xFFFFFFFFFFFFFFFFull;
    const float* fb = f + (n * CC + c) * HW2;
    const float* hb = fhat + (n * CC + c) * HW2;
    float s = 0.f;
    for (int h = 0; h < 16; ++h)
        for (int w = 0; w < 16; ++w)
            s += fb[h * 16 + w] - hb[h * 16 + w];
    rest_t[c * NPAD + n] = s * (1.f / 256.f);
}

// ---------------- argmin: VPT vectors/thread, wave-uniform code loop ----------
// best merge: packed u64 atomicMin (monotonic(dist)<<32 | code) -> exact f32
// order, ties -> smaller code index (numpy argmin semantics).
// launch_bounds(256,1): VGPR cap 512 so the pinned query never spills.
template<int VPT>
__global__ __launch_bounds__(256, 1)
void k_argmin1(const float* __restrict__ rest_t, const float* __restrict__ emb,
               const float* __restrict__ esq, unsigned long long* __restrict__ best,
               int Ntot, int cpw) {
    int tid = threadIdx.x;
    int base = blockIdx.x * (256 * VPT) + tid;
    int v0 = blockIdx.y * cpw;
    float x[VPT][CC];
    bool valid[VPT];
    int nidx[VPT];
    #pragma unroll
    for (int p = 0; p < VPT; ++p) {
        int n = base + p * 256;
        nidx[p] = n;
        valid[p] = (n < Ntot);
        int nc = valid[p] ? n : 0;
        #pragma unroll
        for (int c = 0; c < CC; ++c) x[p][c] = rest_t[c * NPAD + nc];   // coalesced
    }
    // pin the query in VGPRs: values become opaque -> no rematerialization
    #pragma unroll
    for (int p = 0; p < VPT; ++p)
        #pragma unroll
        for (int c = 0; c < CC; ++c)
            asm volatile("" : "+v"(x[p][c]));
    float xx[VPT];
    #pragma unroll
    for (int p = 0; p < VPT; ++p) {
        float s = 0.f;
        #pragma unroll
        for (int c = 0; c < CC; ++c) s = fmaf(x[p][c], x[p][c], s);
        xx[p] = s;
    }
    float bd[VPT];
    int bi[VPT];
    #pragma unroll
    for (int p = 0; p < VPT; ++p) { bd[p] = 3.4e38f; bi[p] = v0; }

    #pragma unroll 2
    for (int v = v0; v < v0 + cpw; ++v) {
        const float* e = emb + v * CC;   // wave-uniform -> s_load
        float d0[VPT], d1[VPT], d2[VPT], d3[VPT];
        #pragma unroll
        for (int p = 0; p < VPT; ++p) { d0[p]=0.f; d1[p]=0.f; d2[p]=0.f; d3[p]=0.f; }
        #pragma unroll
        for (int c = 0; c < CC; c += 4) {
            float e0 = e[c], e1 = e[c+1], e2 = e[c+2], e3 = e[c+3];
            #pragma unroll
            for (int p = 0; p < VPT; ++p) {
                d0[p] = fmaf(x[p][c],   e0, d0[p]);
                d1[p] = fmaf(x[p][c+1], e1, d1[p]);
                d2[p] = fmaf(x[p][c+2], e2, d2[p]);
                d3[p] = fmaf(x[p][c+3], e3, d3[p]);
            }
        }
        float ev = esq[v];
        #pragma unroll
        for (int p = 0; p < VPT; ++p) {
            float dist = (xx[p] + ev) - 2.f * ((d0[p] + d1[p]) + (d2[p] + d3[p]));
            if (dist < bd[p]) { bd[p] = dist; bi[p] = v; }
        }
    }
    #pragma unroll
    for (int p = 0; p < VPT; ++p) {
        if (valid[p]) {
            unsigned u = __float_as_uint(bd[p]);
            unsigned long long mono = (u & 0x80000000u)
                ? (unsigned long long)(~u)
                : (unsigned long long)(u | 0x80000000u);
            atomicMin(best + nidx[p], (mono << 32) | (unsigned long long)(unsigned)bi[p]);
        }
    }
}

// ---------------- fused: gather + upsample + conv3x3(phi) + f_hat + loss
//                  + pool(next scale) + best-init(next scale)
// 512 threads: thread = (pixel, half); half owns 16 staging channels and
// 4 output channels -> 8 waves/block for latency hiding.
__global__ __launch_bounds__(512)
void k_fuse(const float* __restrict__ emb,
            const unsigned long long* __restrict__ best,
            const float* __restrict__ pw, const float* __restrict__ pb,
            const float* __restrict__ f, float* __restrict__ fhat,
            float* __restrict__ loss,
            float* __restrict__ rest_t,
            unsigned long long* __restrict__ best_next,
            int pn, int k, int pn_next) {
    __shared__ float h_up[CC][HW2];
    __shared__ float extra[CC * 169];   // hs during upsample, then diff[8][256]
    __shared__ float red[8];
    int b = blockIdx.x, coq = blockIdx.y, t = threadIdx.x;
    int nn = pn * pn;
    int pix = t & 255, half = t >> 8;
    int y = pix >> 4, x = pix & 15;
    int c0 = half * 16;

    if (pn == 16) {
        int id = (int)(unsigned)(best[b * HW2 + pix] & 0xFFFFFFFFull);
        const float* er = emb + id * CC + c0;
        #pragma unroll
        for (int c = 0; c < 16; ++c) h_up[c0 + c][pix] = er[c];
    } else {
        float (*hs)[169] = (float(*)[169])extra;
        for (int cell = t; cell < nn; cell += 512) {
            int id = (int)(unsigned)(best[b * nn + cell] & 0xFFFFFFFFull);
            const float* er = emb + id * CC;
            #pragma unroll
            for (int c = 0; c < CC; ++c) hs[c][cell] = er[c];
        }
        __syncthreads();
        float scale = (float)pn / 16.f;
        float sy = (y + 0.5f) * scale - 0.5f;
        sy = fminf(fmaxf(sy, 0.f), (float)(pn - 1));
        int y0 = (int)sy; int y1 = min(y0 + 1, pn - 1); float wy = sy - (float)y0;
        float sx = (x + 0.5f) * scale - 0.5f;
        sx = fminf(fmaxf(sx, 0.f), (float)(pn - 1));
        int x0 = (int)sx; int x1 = min(x0 + 1, pn - 1); float wx = sx - (float)x0;
        float wy0 = 1.f - wy, wx0 = 1.f - wx;
        #pragma unroll
        for (int c = 0; c < 16; ++c) {
            int cc = c0 + c;
            float v00 = hs[cc][y0 * pn + x0], v01 = hs[cc][y0 * pn + x1];
            float v10 = hs[cc][y1 * pn + x0], v11 = hs[cc][y1 * pn + x1];
            float a0 = wy0 * v00 + wy * v10;   // contract H first (jax resize order)
            float a1 = wy0 * v01 + wy * v11;
            h_up[cc][pix] = wx0 * a0 + wx * a1;
        }
    }
    __syncthreads();   // h_up ready; all reads of hs/extra done

    float acc[4];
    #pragma unroll
    for (int o = 0; o < 4; ++o) acc[o] = 0.f;
    for (int ci_ = 0; ci_ < CC; ++ci_) {
        float hv[9];
        #pragma unroll
        for (int dy = 0; dy < 3; ++dy)
            #pragma unroll
            for (int dx = 0; dx < 3; ++dx) {
                int yy = y + dy - 1, xx2 = x + dx - 1;
                hv[dy * 3 + dx] = (yy >= 0 && yy < 16 && xx2 >= 0 && xx2 < 16)
                                  ? h_up[ci_][yy * 16 + xx2] : 0.f;
            }
        const float* wp = pw + ((k * CC + coq * 8 + half * 4) * CC + ci_) * 9;  // wave-uniform
        #pragma unroll
        for (int o = 0; o < 4; ++o) {
            const float* w9 = wp + o * (CC * 9);
            #pragma unroll
            for (int q = 0; q < 9; ++q) acc[o] = fmaf(hv[q], w9[q], acc[o]);
        }
    }

    float* diff = extra;   // [8][256], safe: extra unread after the h_up barrier
    float lsum = 0.f;
    #pragma unroll
    for (int o = 0; o < 4; ++o) {
        int lo = half * 4 + o;
        int co = coq * 8 + lo;
        float hval = h_up[co][pix];
        float outv = hval * 0.5f + (acc[o] + pb[k * CC + co]) * 0.5f;
        int pos = (b * CC + co) * HW2 + pix;
        float fh = fhat[pos] + outv;
        fhat[pos] = fh;
        float dd = f[pos] - fh;        // used for loss AND next-scale pooling
        diff[lo * HW2 + pix] = dd;
        lsum = fmaf(dd, dd, lsum);
    }
    #pragma unroll
    for (int off = 32; off > 0; off >>= 1) lsum += __shfl_down(lsum, off, 64);
    if ((t & 63) == 0) red[t >> 6] = lsum;
    __syncthreads();   // red + diff visible
    if (t == 0) {
        float s = 0.f;
        #pragma unroll
        for (int w = 0; w < 8; ++w) s += red[w];
        atomicAdd(loss, s);
    }

    if (pn_next > 0) {
        int nn2 = pn_next * pn_next;
        for (int q = t; q < nn2 * 8; q += 512) {
            int cell = q % nn2, o = q / nn2;
            int i = cell / pn_next, j = cell % pn_next;
            int s0 = (i * 16) / pn_next, e0 = ((i + 1) * 16 + pn_next - 1) / pn_next;
            int s1 = (j * 16) / pn_next, e1 = ((j + 1) * 16 + pn_next - 1) / pn_next;
            float inv = 1.f / (float)((e0 - s0) * (e1 - s1));
            float s = 0.f;
            for (int h = s0; h < e0; ++h)
                for (int w = s1; w < e1; ++w)
                    s += diff[o * HW2 + h * 16 + w];
            rest_t[(coq * 8 + o) * NPAD + b * nn2 + cell] = s * inv;
        }
        if (coq == 0)
            for (int q = t; q < nn2; q += 512)
                best_next[b * nn2 + q] = 0xFFFFFFFFFFFFFFFFull;
    }
}

// ---------------- writeout: f32 -> out dtype (matches probed input dtype) ----------------
__global__ void k_out(const float* __restrict__ fhat, const float* __restrict__ loss,
                      const int* __restrict__ flag, void* __restrict__ out) {
    bool isf32 = (*flag != 0);
    int i = blockIdx.x * 256 + threadIdx.x;
    if (i > NELEM) return;
    float v;
    if (i < NELEM) v = fhat[i];
    else           v = (*loss) * (1.25f / (float)NELEM / 8.f);
    if (isf32) ((float*)out)[i] = v;
    else       ((__hip_bfloat16*)out)[i] = __float2bfloat16(v);
}

extern "C" void kernel_launch(void* const* d_in, const int* in_sizes, int n_in,
                              void* d_out, int out_size, void* d_ws, size_t ws_size,
                              hipStream_t stream) {
    const void* fin  = d_in[0];
    const void* ein  = d_in[1];
    const void* win  = d_in[2];
    const void* bin_ = d_in[3];
    float* ws = (float*)d_ws;
    float* f    = ws + OFF_F;
    float* fhat = ws + OFF_FHAT;
    float* emb  = ws + OFF_EMB;
    float* esq  = ws + OFF_ESQ;
    float* pw   = ws + OFF_PW;
    float* pb   = ws + OFF_PB;
    float* rest_t = ws + OFF_REST;
    unsigned long long* bestA = (unsigned long long*)(ws + OFF_BESTA);
    unsigned long long* bestB = (unsigned long long*)(ws + OFF_BESTB);
    float* loss = ws + OFF_LOSS;
    int*   flag = (int*)(ws + OFF_FLAG);

    static const int PN[8]  = {1, 2, 4, 6, 8, 10, 13, 16};
    static const int KK[8]  = {0, 0, 1, 1, 2, 2, 3, 3};
    static const int SP[8]  = {64, 64, 64, 64, 64, 32, 32, 32};
    static const int VPT[8] = {1, 1, 1, 1, 2, 2, 2, 2};

    k_probe<<<1, 256, 0, stream>>>(fin, flag);
    k_prep<<<(NELEM + 255) / 256, 256, 0, stream>>>(fin, ein, win, bin_, flag, f, fhat, emb, pw, pb, loss);
    k_esq<<<(VV + 255) / 256, 256, 0, stream>>>(emb, esq);
    k_pool0<<<dim3(1, CC), 256, 0, stream>>>(f, fhat, rest_t, bestA);

    for (int si = 0; si < 8; ++si) {
        int pn = PN[si];
        int Ntot = BB * pn * pn;
        int Sp = SP[si];
        int cpw = VV / Sp;
        unsigned long long* bcur = (si & 1) ? bestB : bestA;
        unsigned long long* bnxt = (si & 1) ? bestA : bestB;
        int pn_next = (si < 7) ? PN[si + 1] : 0;
        if (VPT[si] == 2) {
            int gx = (Ntot + 511) / 512;
            k_argmin1<2><<<dim3(gx, Sp), 256, 0, stream>>>(rest_t, emb, esq, bcur, Ntot, cpw);
        } else {
            int gx = (Ntot + 255) / 256;
            k_argmin1<1><<<dim3(gx, Sp), 256, 0, stream>>>(rest_t, emb, esq, bcur, Ntot, cpw);
        }
        k_fuse<<<dim3(BB, 4), 512, 0, stream>>>(emb, bcur, pw, pb, f, fhat, loss,
                                                rest_t, bnxt, pn, KK[si], pn_next);
    }
    k_out<<<(NELEM + 1 + 255) / 256, 256, 0, stream>>>(fhat, loss, flag, d_out);
}